// Round 19
// baseline (84.583 us; speedup 1.0000x reference)
//
#include <hip/hip_runtime.h>
#include <hip/hip_bf16.h>
#include <hip/hip_fp8.h>

#define N_ROWS 16384
#define M_ROWS 16384
#define DIM 256
#define JT 32           // y-cols per j-iter
#define NJ 32           // j-iters per block (JT*NJ = 1024-col chunk)

typedef __attribute__((ext_vector_type(4))) float f32x4;
typedef __attribute__((ext_vector_type(4))) int   i32x4;
typedef __attribute__((ext_vector_type(8))) int   i32x8;

__device__ inline unsigned enc_f(float f) {
  unsigned u = __float_as_uint(f);
  return (u & 0x80000000u) ? ~u : (u | 0x80000000u);
}
__device__ inline float dec_f(unsigned u) {
  unsigned b = (u & 0x80000000u) ? (u & 0x7FFFFFFFu) : ~u;
  return __uint_as_float(b);
}

// Fused prep: blocks [0,4096) convert x -> xb8 (fp8 e4m3) + x2 + rowmin init;
// blocks [4096,8192) convert y -> yb8 + (y2 - psi). Row sums stay fp32-exact
// from the ORIGINAL floats; only the cross term is quantized.
__global__ __launch_bounds__(256) void prep_kernel(
    const float* __restrict__ x, const float* __restrict__ y,
    const float* __restrict__ psi,
    unsigned char* __restrict__ xb8, unsigned char* __restrict__ yb8,
    float* __restrict__ x2, float* __restrict__ rj,
    unsigned int* __restrict__ rowmin) {
  int bid  = blockIdx.x;
  int isY  = bid >= (N_ROWS / 4);
  int rb   = isY ? bid - N_ROWS / 4 : bid;
  int row  = rb * 4 + (threadIdx.x >> 6);
  int lane = threadIdx.x & 63;
  const float* in = isY ? y : x;
  unsigned char* outb = isY ? yb8 : xb8;
  const float4 v = *reinterpret_cast<const float4*>(in + (size_t)row * DIM + lane * 4);
  unsigned b0 = __hip_fp8_e4m3(v.x).__x;
  unsigned b1 = __hip_fp8_e4m3(v.y).__x;
  unsigned b2 = __hip_fp8_e4m3(v.z).__x;
  unsigned b3 = __hip_fp8_e4m3(v.w).__x;
  *reinterpret_cast<unsigned int*>(outb + (size_t)row * DIM + lane * 4) =
      b0 | (b1 << 8) | (b2 << 16) | (b3 << 24);
  float s = v.x * v.x + v.y * v.y + v.z * v.z + v.w * v.w;
#pragma unroll
  for (int m = 1; m < 64; m <<= 1) s += __shfl_xor(s, m, 64);
  if (lane == 0) {
    if (isY) rj[row] = s - psi[row];
    else { x2[row] = s; rowmin[row] = 0xFFFFFFFFu; }
  }
}

// R18 skeleton (MX-scaled fp8 K=128, unit scales), grid-doubled: 16 column
// chunks of 1024 cols -> 1024 blocks = 4/CU (3 resident at 136 regs/wave).
// Cross-block anti-phase fills the matrix pipe during stage/fold phases.
__global__ __launch_bounds__(256, 3) void gemm_min_kernel(
    const unsigned char* __restrict__ xb8, const unsigned char* __restrict__ yb8,
    const float* __restrict__ rj, unsigned int* __restrict__ rowmin) {
  __shared__ unsigned char Bt[3][JT * DIM];  // 3 x 8 KiB

  const int bid    = blockIdx.x;       // 1024 blocks, 4 per CU
  const int jchunk = bid & 15;         // (jchunk&7) == XCD id under round-robin
  const int strip  = bid >> 4;         // 0..63
  const int brow   = strip * 256;
  const int jbase0 = jchunk * (JT * NJ);

  const int tid = threadIdx.x;
  const int w = tid >> 6, lane = tid & 63;
  const int fr = lane & 15, g4 = lane >> 4;

  const int SC1 = 0x7F7F7F7F;  // E8M0 unit scales for all block-select bytes

  // ---- A fragments (16x16x128): row = brow + w*64 + m*16 + fr,
  // k = kq*128 + g4*32 .. +32 (32 contiguous bytes/lane); AGPR-pinned.
  i32x8 afr[4][2];
  {
    const unsigned char* aBase = xb8 + (size_t)(brow + w * 64 + fr) * DIM + g4 * 32;
#pragma unroll
    for (int m = 0; m < 4; ++m)
#pragma unroll
      for (int kq = 0; kq < 2; ++kq) {
        afr[m][kq] = *reinterpret_cast<const i32x8*>(aBase + (size_t)(m * 16) * DIM + kq * 128);
        asm volatile("" : "+a"(afr[m][kq]));  // pin in AGPR file
      }
  }
  __builtin_amdgcn_sched_barrier(0);

  // ---- staging: 8 pieces x 1KB per tile; wave w stages pieces w*2, w*2+1.
  // piece p: chunk cc = p>>1, half h = p&1. LDS dest lane-linear; per-lane
  // global source row (cc>>1)*16+(lane&15), k = (cc&1)*128 + (lane>>4)*32 + h*16.
  const int sr16 = lane & 15;
  const int sk32 = (lane >> 4) * 32;

#define STAGE(buf, j)                                                            \
  {                                                                              \
    _Pragma("unroll")                                                            \
    for (int c = 0; c < 2; ++c) {                                                \
      const int p = w * 2 + c;                                                   \
      const int cc = p >> 1, h = p & 1;                                          \
      __builtin_amdgcn_global_load_lds(                                          \
          (const __attribute__((address_space(1))) void*)(                       \
              yb8 + (size_t)(jbase0 + (j) * JT + (cc >> 1) * 16 + sr16) * DIM +  \
              (cc & 1) * 128 + sk32 + h * 16),                                   \
          (__attribute__((address_space(3))) void*)(&Bt[(buf)][cc * 2048 + h * 1024]), \
          16, 0, 0);                                                             \
    }                                                                            \
  }

  // LOADF: B fragment for group g (kq = g>>1, ng = g&1; chunk cc = ng*2+kq):
  // two lane-linear b128 reads (conflict-free).
#define LOADF(dst, g)                                                            \
  {                                                                              \
    const int cc = ((g) & 1) * 2 + ((g) >> 1);                                   \
    i32x4 lo = *reinterpret_cast<const i32x4*>(&B[cc * 2048 + lane * 16]);       \
    i32x4 hi = *reinterpret_cast<const i32x4*>(&B[cc * 2048 + 1024 + lane * 16]); \
    dst[0] = lo[0]; dst[1] = lo[1]; dst[2] = lo[2]; dst[3] = lo[3];              \
    dst[4] = hi[0]; dst[5] = hi[1]; dst[6] = hi[2]; dst[7] = hi[3];              \
  }

#define MFMA4(KQ, NG, PB)                                                        \
  {                                                                              \
    _Pragma("unroll")                                                            \
    for (int m = 0; m < 4; ++m)                                                  \
      acc[m][(NG)] = __builtin_amdgcn_mfma_scale_f32_16x16x128_f8f6f4(           \
          afr[m][(KQ)], PB, acc[m][(NG)], 0, 0, 0, SC1, 0, SC1);                 \
  }

  STAGE(0, 0);
  STAGE(1, 1);

  const float* rjc = rj + jbase0;
  float mn[4][4];
#pragma unroll
  for (int m = 0; m < 4; ++m)
#pragma unroll
    for (int r = 0; r < 4; ++r) mn[m][r] = 3.4e38f;

  int rb = 0;  // ring read index
#pragma unroll 1
  for (int j = 0; j < NJ; ++j) {
    if (j == NJ - 1) { asm volatile("s_waitcnt vmcnt(0)" ::: "memory"); }
    else             { asm volatile("s_waitcnt vmcnt(2)" ::: "memory"); }
    __builtin_amdgcn_sched_barrier(0);
    __builtin_amdgcn_s_barrier();
    __builtin_amdgcn_sched_barrier(0);

    // rv loads issued early; consumed only at iter end (latency hidden by MFMA).
    float rv0 = rjc[j * JT + fr];
    float rv1 = rjc[j * JT + 16 + fr];
    __builtin_amdgcn_sched_barrier(0);
    if (j + 2 < NJ) {
      int sb = rb + 2; if (sb >= 3) sb -= 3;
      STAGE(sb, j + 2);
    }
    __builtin_amdgcn_sched_barrier(0);

    f32x4 acc[4][2];
#pragma unroll
    for (int m = 0; m < 4; ++m)
#pragma unroll
      for (int n = 0; n < 2; ++n) acc[m][n] = (f32x4){0.f, 0.f, 0.f, 0.f};

    const unsigned char* B = &Bt[rb][0];
    i32x8 pbA, pbB;
    LOADF(pbA, 0);

    __builtin_amdgcn_s_setprio(1);
    __builtin_amdgcn_sched_barrier(0);
    // g=0: (kq0, ng0)
    LOADF(pbB, 1);
    MFMA4(0, 0, pbA);
    __builtin_amdgcn_sched_group_barrier(0x100, 2, 0);
    __builtin_amdgcn_sched_group_barrier(0x008, 4, 0);
    // g=1: (kq0, ng1)
    LOADF(pbA, 2);
    MFMA4(0, 1, pbB);
    __builtin_amdgcn_sched_group_barrier(0x100, 2, 0);
    __builtin_amdgcn_sched_group_barrier(0x008, 4, 0);
    // g=2: (kq1, ng0)
    LOADF(pbB, 3);
    MFMA4(1, 0, pbA);
    __builtin_amdgcn_sched_group_barrier(0x100, 2, 0);
    __builtin_amdgcn_sched_group_barrier(0x008, 4, 0);
    // g=3: (kq1, ng1)
    MFMA4(1, 1, pbB);
    __builtin_amdgcn_sched_group_barrier(0x008, 4, 0);
    __builtin_amdgcn_sched_barrier(0);
    __builtin_amdgcn_s_setprio(0);

    // fold: val = rv - 2*dot ; running min
#pragma unroll
    for (int m = 0; m < 4; ++m)
#pragma unroll
      for (int r = 0; r < 4; ++r) {
        mn[m][r] = fminf(mn[m][r], fmaf(-2.f, acc[m][0][r], rv0));
        mn[m][r] = fminf(mn[m][r], fmaf(-2.f, acc[m][1][r], rv1));
      }
    rb = rb + 1; if (rb >= 3) rb -= 3;
  }
#undef MFMA4
#undef LOADF
#undef STAGE

  // Row-min over chunk: reduce min over the 16 fr-lanes, then one atomic per row.
#pragma unroll
  for (int m = 0; m < 4; ++m)
#pragma unroll
    for (int r = 0; r < 4; ++r) {
      float v = mn[m][r];
#pragma unroll
      for (int s = 1; s < 16; s <<= 1) v = fminf(v, __shfl_xor(v, s, 64));
      if (fr == 0) {
        int row = brow + w * 64 + m * 16 + g4 * 4 + r;
        atomicMin(&rowmin[row], enc_f(v));
      }
    }
}

// Stage 1: 64 blocks; block b sums rows [b*256, (b+1)*256) of x2+rowmin (and
// psi) into partials — fixed reduction order, deterministic.
__global__ __launch_bounds__(256) void finish1_kernel(
    const float* __restrict__ x2, const unsigned int* __restrict__ rowmin,
    const float* __restrict__ psi, double* __restrict__ partials) {
  int tid = threadIdx.x;
  int i = blockIdx.x * 256 + tid;
  double s0 = (double)x2[i] + (double)dec_f(rowmin[i]);
  double s1 = (double)psi[i];
  __shared__ double sm0[4], sm1[4];
#pragma unroll
  for (int m = 1; m < 64; m <<= 1) { s0 += __shfl_xor(s0, m, 64); s1 += __shfl_xor(s1, m, 64); }
  if ((tid & 63) == 0) { sm0[tid >> 6] = s0; sm1[tid >> 6] = s1; }
  __syncthreads();
  if (tid == 0) {
    partials[blockIdx.x]      = sm0[0] + sm0[1] + sm0[2] + sm0[3];
    partials[64 + blockIdx.x] = sm1[0] + sm1[1] + sm1[2] + sm1[3];
  }
}

// Stage 2: one wave reduces the 64 partials.
__global__ __launch_bounds__(64) void finish2_kernel(
    const double* __restrict__ partials, float* __restrict__ out) {
  int lane = threadIdx.x;
  double s0 = partials[lane];
  double s1 = partials[64 + lane];
#pragma unroll
  for (int m = 1; m < 64; m <<= 1) { s0 += __shfl_xor(s0, m, 64); s1 += __shfl_xor(s1, m, 64); }
  if (lane == 0) {
    out[0] = (float)(s0 / (double)N_ROWS);
    out[1] = (float)(s1 / (double)M_ROWS);
  }
}

extern "C" void kernel_launch(void* const* d_in, const int* in_sizes, int n_in,
                              void* d_out, int out_size, void* d_ws, size_t ws_size,
                              hipStream_t stream) {
  const float* x   = (const float*)d_in[0];
  const float* y   = (const float*)d_in[1];
  const float* psi = (const float*)d_in[2];
  float* out = (float*)d_out;

  char* ws = (char*)d_ws;
  unsigned char* xb8 = (unsigned char*)ws;                                   // 4 MB
  unsigned char* yb8 = (unsigned char*)(ws + (size_t)N_ROWS * DIM);          // 4 MB
  float* x2 = (float*)(ws + (size_t)(N_ROWS + M_ROWS) * DIM);                // 64 KB
  float* rj = x2 + N_ROWS;                                                   // 64 KB (y2 - psi)
  unsigned int* rowmin = (unsigned int*)(rj + M_ROWS);                       // 64 KB
  double* partials = (double*)(rowmin + N_ROWS);                             // 1 KB

  prep_kernel<<<(N_ROWS + M_ROWS) / 4, 256, 0, stream>>>(x, y, psi, xb8, yb8, x2, rj, rowmin);
  gemm_min_kernel<<<(N_ROWS / 256) * 16, 256, 0, stream>>>(xb8, yb8, rj, rowmin);
  finish1_kernel<<<N_ROWS / 256, 256, 0, stream>>>(x2, rowmin, psi, partials);
  finish2_kernel<<<1, 64, 0, stream>>>(partials, out);
}

// Round 20
// 78.042 us; speedup vs baseline: 1.0838x; 1.0838x over previous
//
#include <hip/hip_runtime.h>
#include <hip/hip_bf16.h>
#include <hip/hip_fp8.h>

#define N_ROWS 16384
#define M_ROWS 16384
#define DIM 256
#define JT 64           // y-cols per j-iter
#define NJ 32           // j-iters per block (JT*NJ = 2048-col chunk)

typedef __attribute__((ext_vector_type(4))) float f32x4;
typedef __attribute__((ext_vector_type(4))) int   i32x4;
typedef __attribute__((ext_vector_type(8))) int   i32x8;

__device__ inline unsigned enc_f(float f) {
  unsigned u = __float_as_uint(f);
  return (u & 0x80000000u) ? ~u : (u | 0x80000000u);
}
__device__ inline float dec_f(unsigned u) {
  unsigned b = (u & 0x80000000u) ? (u & 0x7FFFFFFFu) : ~u;
  return __uint_as_float(b);
}

// Fused prep: blocks [0,4096) convert x -> xb8 (fp8 e4m3) + x2 + rowmin init;
// blocks [4096,8192) convert y -> yb8 + (y2 - psi). Row sums stay fp32-exact
// from the ORIGINAL floats; only the cross term is quantized.
__global__ __launch_bounds__(256) void prep_kernel(
    const float* __restrict__ x, const float* __restrict__ y,
    const float* __restrict__ psi,
    unsigned char* __restrict__ xb8, unsigned char* __restrict__ yb8,
    float* __restrict__ x2, float* __restrict__ rj,
    unsigned int* __restrict__ rowmin) {
  int bid  = blockIdx.x;
  int isY  = bid >= (N_ROWS / 4);
  int rb   = isY ? bid - N_ROWS / 4 : bid;
  int row  = rb * 4 + (threadIdx.x >> 6);
  int lane = threadIdx.x & 63;
  const float* in = isY ? y : x;
  unsigned char* outb = isY ? yb8 : xb8;
  const float4 v = *reinterpret_cast<const float4*>(in + (size_t)row * DIM + lane * 4);
  unsigned b0 = __hip_fp8_e4m3(v.x).__x;
  unsigned b1 = __hip_fp8_e4m3(v.y).__x;
  unsigned b2 = __hip_fp8_e4m3(v.z).__x;
  unsigned b3 = __hip_fp8_e4m3(v.w).__x;
  *reinterpret_cast<unsigned int*>(outb + (size_t)row * DIM + lane * 4) =
      b0 | (b1 << 8) | (b2 << 16) | (b3 << 24);
  float s = v.x * v.x + v.y * v.y + v.z * v.z + v.w * v.w;
#pragma unroll
  for (int m = 1; m < 64; m <<= 1) s += __shfl_xor(s, m, 64);
  if (lane == 0) {
    if (isY) rj[row] = s - psi[row];
    else { x2[row] = s; rowmin[row] = 0xFFFFFFFFu; }
  }
}

// R18 skeleton with JT=64 (wide tile): MX-scaled fp8 K=128, unit scales.
// 32 MFMAs/wave-iter against the SAME per-phase overhead (amortization).
// Sync skeleton identical to R12-R18: 3-ring, stage j+2, one barrier/iter,
// counted vmcnt(4) (4-instr stage). LDS 3 x 16KB = 48KB -> 2 blocks/CU.
// Tile = 8 chunks x 2KB; chunk cc = n*2+ksub = (16-col group n, 128-k slice
// ksub) fragment set, split in two 1KB lane-linear halves (conflict-free b128).
__global__ __launch_bounds__(256, 2) void gemm_min_kernel(
    const unsigned char* __restrict__ xb8, const unsigned char* __restrict__ yb8,
    const float* __restrict__ rj, unsigned int* __restrict__ rowmin) {
  __shared__ unsigned char Bt[3][JT * DIM];  // 3 x 16 KiB

  const int bid    = blockIdx.x;       // 512 blocks, 2 per CU
  const int jchunk = bid & 7;          // == XCD id under round-robin dispatch
  const int strip  = bid >> 3;         // 0..63
  const int brow   = strip * 256;
  const int jbase0 = jchunk * (JT * NJ);

  const int tid = threadIdx.x;
  const int w = tid >> 6, lane = tid & 63;
  const int fr = lane & 15, g4 = lane >> 4;

  const int SC1 = 0x7F7F7F7F;  // E8M0 unit scales for all block-select bytes

  // ---- A fragments (16x16x128): row = brow + w*64 + m*16 + fr,
  // k = kq*128 + g4*32 .. +32 (32 contiguous bytes/lane); AGPR-pinned.
  i32x8 afr[4][2];
  {
    const unsigned char* aBase = xb8 + (size_t)(brow + w * 64 + fr) * DIM + g4 * 32;
#pragma unroll
    for (int m = 0; m < 4; ++m)
#pragma unroll
      for (int kq = 0; kq < 2; ++kq) {
        afr[m][kq] = *reinterpret_cast<const i32x8*>(aBase + (size_t)(m * 16) * DIM + kq * 128);
        asm volatile("" : "+a"(afr[m][kq]));  // pin in AGPR file
      }
  }
  __builtin_amdgcn_sched_barrier(0);

  // ---- staging: 16 pieces x 1KB per tile; wave w stages pieces w*4..w*4+3.
  // piece p: chunk cc = p>>1 (n = cc>>1, ksub = cc&1), half h = p&1.
  // LDS dest lane-linear; per-lane global source row (cc>>1)*16 + (lane&15),
  // k = (cc&1)*128 + (lane>>4)*32 + h*16.
  const int sr16 = lane & 15;
  const int sk32 = (lane >> 4) * 32;

#define STAGE(buf, j)                                                            \
  {                                                                              \
    _Pragma("unroll")                                                            \
    for (int c = 0; c < 4; ++c) {                                                \
      const int p = w * 4 + c;                                                   \
      const int cc = p >> 1, h = p & 1;                                          \
      __builtin_amdgcn_global_load_lds(                                          \
          (const __attribute__((address_space(1))) void*)(                       \
              yb8 + (size_t)(jbase0 + (j) * JT + (cc >> 1) * 16 + sr16) * DIM +  \
              (cc & 1) * 128 + sk32 + h * 16),                                   \
          (__attribute__((address_space(3))) void*)(&Bt[(buf)][cc * 2048 + h * 1024]), \
          16, 0, 0);                                                             \
    }                                                                            \
  }

  // LOADF: B fragment for (col-group NG, k-quad KQ); chunk cc = NG*2+KQ:
  // two lane-linear b128 reads (conflict-free).
#define LOADF(dst, NG, KQ)                                                       \
  {                                                                              \
    const int cc = (NG) * 2 + (KQ);                                              \
    i32x4 lo = *reinterpret_cast<const i32x4*>(&B[cc * 2048 + lane * 16]);       \
    i32x4 hi = *reinterpret_cast<const i32x4*>(&B[cc * 2048 + 1024 + lane * 16]); \
    dst[0] = lo[0]; dst[1] = lo[1]; dst[2] = lo[2]; dst[3] = lo[3];              \
    dst[4] = hi[0]; dst[5] = hi[1]; dst[6] = hi[2]; dst[7] = hi[3];              \
  }

#define MFMA4(KQ, NG, PB)                                                        \
  {                                                                              \
    _Pragma("unroll")                                                            \
    for (int m = 0; m < 4; ++m)                                                  \
      acc[m][(NG)] = __builtin_amdgcn_mfma_scale_f32_16x16x128_f8f6f4(           \
          afr[m][(KQ)], PB, acc[m][(NG)], 0, 0, 0, SC1, 0, SC1);                 \
  }

#define SGB_DS_MFMA                                                              \
  __builtin_amdgcn_sched_group_barrier(0x100, 2, 0);                             \
  __builtin_amdgcn_sched_group_barrier(0x008, 4, 0);

  STAGE(0, 0);
  STAGE(1, 1);

  const float* rjc = rj + jbase0;
  float mn[4][4];
#pragma unroll
  for (int m = 0; m < 4; ++m)
#pragma unroll
    for (int r = 0; r < 4; ++r) mn[m][r] = 3.4e38f;

  int rb = 0;  // ring read index
#pragma unroll 1
  for (int j = 0; j < NJ; ++j) {
    if (j == NJ - 1) { asm volatile("s_waitcnt vmcnt(0)" ::: "memory"); }
    else             { asm volatile("s_waitcnt vmcnt(4)" ::: "memory"); }
    __builtin_amdgcn_sched_barrier(0);
    __builtin_amdgcn_s_barrier();
    __builtin_amdgcn_sched_barrier(0);

    // rv loads issued early; consumed only at iter end (latency hidden by MFMA).
    float rv[4];
#pragma unroll
    for (int n = 0; n < 4; ++n) rv[n] = rjc[j * JT + n * 16 + fr];
    __builtin_amdgcn_sched_barrier(0);
    if (j + 2 < NJ) {
      int sb = rb + 2; if (sb >= 3) sb -= 3;
      STAGE(sb, j + 2);
    }
    __builtin_amdgcn_sched_barrier(0);

    f32x4 acc[4][4];
#pragma unroll
    for (int m = 0; m < 4; ++m)
#pragma unroll
      for (int n = 0; n < 4; ++n) acc[m][n] = (f32x4){0.f, 0.f, 0.f, 0.f};

    const unsigned char* B = &Bt[rb][0];
    i32x8 pbA, pbB;
    LOADF(pbA, 0, 0);

    __builtin_amdgcn_s_setprio(1);
    __builtin_amdgcn_sched_barrier(0);
    LOADF(pbB, 1, 0); MFMA4(0, 0, pbA); SGB_DS_MFMA;
    LOADF(pbA, 2, 0); MFMA4(0, 1, pbB); SGB_DS_MFMA;
    LOADF(pbB, 3, 0); MFMA4(0, 2, pbA); SGB_DS_MFMA;
    LOADF(pbA, 0, 1); MFMA4(0, 3, pbB); SGB_DS_MFMA;
    LOADF(pbB, 1, 1); MFMA4(1, 0, pbA); SGB_DS_MFMA;
    LOADF(pbA, 2, 1); MFMA4(1, 1, pbB); SGB_DS_MFMA;
    LOADF(pbB, 3, 1); MFMA4(1, 2, pbA); SGB_DS_MFMA;
    MFMA4(1, 3, pbB);
    __builtin_amdgcn_sched_group_barrier(0x008, 4, 0);
    __builtin_amdgcn_sched_barrier(0);
    __builtin_amdgcn_s_setprio(0);

    // fold: val = rv - 2*dot ; running min
#pragma unroll
    for (int m = 0; m < 4; ++m)
#pragma unroll
      for (int n = 0; n < 4; ++n)
#pragma unroll
        for (int r = 0; r < 4; ++r)
          mn[m][r] = fminf(mn[m][r], fmaf(-2.f, acc[m][n][r], rv[n]));
    rb = rb + 1; if (rb >= 3) rb -= 3;
  }
#undef SGB_DS_MFMA
#undef MFMA4
#undef LOADF
#undef STAGE

  // Row-min over chunk: reduce min over the 16 fr-lanes, then one atomic per row.
#pragma unroll
  for (int m = 0; m < 4; ++m)
#pragma unroll
    for (int r = 0; r < 4; ++r) {
      float v = mn[m][r];
#pragma unroll
      for (int s = 1; s < 16; s <<= 1) v = fminf(v, __shfl_xor(v, s, 64));
      if (fr == 0) {
        int row = brow + w * 64 + m * 16 + g4 * 4 + r;
        atomicMin(&rowmin[row], enc_f(v));
      }
    }
}

// Stage 1: 64 blocks; block b sums rows [b*256, (b+1)*256) of x2+rowmin (and
// psi) into partials — fixed reduction order, deterministic.
__global__ __launch_bounds__(256) void finish1_kernel(
    const float* __restrict__ x2, const unsigned int* __restrict__ rowmin,
    const float* __restrict__ psi, double* __restrict__ partials) {
  int tid = threadIdx.x;
  int i = blockIdx.x * 256 + tid;
  double s0 = (double)x2[i] + (double)dec_f(rowmin[i]);
  double s1 = (double)psi[i];
  __shared__ double sm0[4], sm1[4];
#pragma unroll
  for (int m = 1; m < 64; m <<= 1) { s0 += __shfl_xor(s0, m, 64); s1 += __shfl_xor(s1, m, 64); }
  if ((tid & 63) == 0) { sm0[tid >> 6] = s0; sm1[tid >> 6] = s1; }
  __syncthreads();
  if (tid == 0) {
    partials[blockIdx.x]      = sm0[0] + sm0[1] + sm0[2] + sm0[3];
    partials[64 + blockIdx.x] = sm1[0] + sm1[1] + sm1[2] + sm1[3];
  }
}

// Stage 2: one wave reduces the 64 partials.
__global__ __launch_bounds__(64) void finish2_kernel(
    const double* __restrict__ partials, float* __restrict__ out) {
  int lane = threadIdx.x;
  double s0 = partials[lane];
  double s1 = partials[64 + lane];
#pragma unroll
  for (int m = 1; m < 64; m <<= 1) { s0 += __shfl_xor(s0, m, 64); s1 += __shfl_xor(s1, m, 64); }
  if (lane == 0) {
    out[0] = (float)(s0 / (double)N_ROWS);
    out[1] = (float)(s1 / (double)M_ROWS);
  }
}

extern "C" void kernel_launch(void* const* d_in, const int* in_sizes, int n_in,
                              void* d_out, int out_size, void* d_ws, size_t ws_size,
                              hipStream_t stream) {
  const float* x   = (const float*)d_in[0];
  const float* y   = (const float*)d_in[1];
  const float* psi = (const float*)d_in[2];
  float* out = (float*)d_out;

  char* ws = (char*)d_ws;
  unsigned char* xb8 = (unsigned char*)ws;                                   // 4 MB
  unsigned char* yb8 = (unsigned char*)(ws + (size_t)N_ROWS * DIM);          // 4 MB
  float* x2 = (float*)(ws + (size_t)(N_ROWS + M_ROWS) * DIM);                // 64 KB
  float* rj = x2 + N_ROWS;                                                   // 64 KB (y2 - psi)
  unsigned int* rowmin = (unsigned int*)(rj + M_ROWS);                       // 64 KB
  double* partials = (double*)(rowmin + N_ROWS);                             // 1 KB

  prep_kernel<<<(N_ROWS + M_ROWS) / 4, 256, 0, stream>>>(x, y, psi, xb8, yb8, x2, rj, rowmin);
  gemm_min_kernel<<<(N_ROWS / 256) * 8, 256, 0, stream>>>(xb8, yb8, rj, rowmin);
  finish1_kernel<<<N_ROWS / 256, 256, 0, stream>>>(x2, rowmin, psi, partials);
  finish2_kernel<<<1, 64, 0, stream>>>(partials, out);
}